// Round 1
// baseline (1434.322 us; speedup 1.0000x reference)
//
#include <hip/hip_runtime.h>
#include <hip/hip_bf16.h>
#include <math.h>

#define H_DIM  1152
#define FL_DIM 1152
#define FH_DIM 4608
#define NTOK   32768
#define FL_PAD 1280   // light N padded to 5*256 (gemm1 B rows)
#define H_PAD  1280   // gemm2 out-cols padded to 5*256 (W2 rows)

typedef __attribute__((ext_vector_type(8))) short bf16x8;
typedef __attribute__((ext_vector_type(4))) float floatx4;
typedef __attribute__((ext_vector_type(4))) unsigned short ushort4v;

__device__ __forceinline__ unsigned short f2bf(float f) {
  union { float f; unsigned int i; } v; v.f = f;
  return (unsigned short)((v.i + 0x7FFFu + ((v.i >> 16) & 1u)) >> 16);
}

// ---------------- fp32 -> bf16 conversion (weights) -------------------------
__global__ __launch_bounds__(256) void cvt_kernel(
    const float* __restrict__ in, unsigned short* __restrict__ out, int n4) {
  const int i = blockIdx.x * 256 + threadIdx.x;
  if (i >= n4) return;
  const float4 v = ((const float4*)in)[i];
  ushort4v o;
  o[0] = f2bf(v.x); o[1] = f2bf(v.y); o[2] = f2bf(v.z); o[3] = f2bf(v.w);
  ((ushort4v*)out)[i] = o;
}

// ------- router + x cvt: p1[t] = sigmoid(l1-l0); xb = bf16(x) ---------------
__global__ __launch_bounds__(256) void router_cvt_kernel(
    const float* __restrict__ x,   // [NTOK, H] fp32
    const float* __restrict__ rw,  // [2, H]
    const float* __restrict__ rb,  // [2]
    float* __restrict__ p1out,     // [NTOK]
    unsigned short* __restrict__ xb) {  // [NTOK, H] bf16
  const int wave = threadIdx.x >> 6;
  const int lane = threadIdx.x & 63;
  const int tok = blockIdx.x * 4 + wave;
  const float* xr = x + (size_t)tok * H_DIM;
  unsigned short* xo = xb + (size_t)tok * H_DIM;
  float s0 = 0.f, s1 = 0.f;
#pragma unroll
  for (int j = 0; j < H_DIM / 64; ++j) {
    const int h = j * 64 + lane;
    const float xv = xr[h];
    xo[h] = f2bf(xv);
    s0 += xv * rw[h];
    s1 += xv * rw[H_DIM + h];
  }
  for (int off = 32; off > 0; off >>= 1) {
    s0 += __shfl_down(s0, off);
    s1 += __shfl_down(s1, off);
  }
  if (lane == 0) {
    const float l0 = s0 + rb[0];
    const float l1 = s1 + rb[1];
    p1out[tok] = 1.f / (1.f + expf(l0 - l1));
  }
}

// ===================== 256x256 8-phase pipelined GEMM =======================
// 512 threads = 8 waves (2m x 4n), per-wave output 128x64 (8x4 frags 16x16).
// LDS: A[2][256][64] + B[2][256][64] bf16 = 128 KiB double buffer.
// Tiles staged with global_load_lds (16B); chunk column XOR-swizzled by
// (row&7) so ds_read_b128 frag reads are 2-way bank-aliased (free).
// Per K-tile: 4 phases x {ds_read subtile | stage prefetch -> s_barrier ->
// lgkmcnt(0) -> setprio(1) 16xMFMA setprio(0) -> s_barrier}.
// Counted vmcnt(4) once per K-tile keeps next-tile loads in flight across
// barriers (never drain to 0 in steady state).
//   stage plan, iteration u (parity c=u&1):
//     P0: A(u+1) full -> As[c^1]   (As[c^1] free since P3(u-1))
//     P1: B(u+2) rows 0..127 -> Bs[c]  (Bs[c] consumed in P0: B hoisted)
//     P2: B(u+2) rows 128..255 -> Bs[c]
//     P3: vmcnt(4) keeps exactly the 4 B(u+2) loads outstanding, drains
//         A(u+1), B(u+1) -> safe for P0(u+1) reads.

struct Offs { int o0, o1, o2, o3; };

__device__ __forceinline__ Offs make_offs(int tid, int lda) {
  Offs o;
  const int c0 = tid, c1 = 512 + tid, c2 = 1024 + tid, c3 = 1536 + tid;
  const int r0 = c0 >> 3, r1 = c1 >> 3, r2 = c2 >> 3, r3 = c3 >> 3;
  o.o0 = r0 * lda + (((c0 & 7) ^ (r0 & 7)) << 3);
  o.o1 = r1 * lda + (((c1 & 7) ^ (r1 & 7)) << 3);
  o.o2 = r2 * lda + (((c2 & 7) ^ (r2 & 7)) << 3);
  o.o3 = r3 * lda + (((c3 & 7) ^ (r3 & 7)) << 3);
  return o;
}

__device__ __forceinline__ void stage_slot(const unsigned short* g, int off,
                                           unsigned short* lds, int slot, int w) {
  __builtin_amdgcn_global_load_lds(
      (const __attribute__((address_space(1))) void*)(g + off),
      (__attribute__((address_space(3))) void*)(lds + slot * 4096 + w * 512),
      16, 0, 0);
}

__device__ __forceinline__ void stage4(const unsigned short* g, const Offs& o,
                                       unsigned short* lds, int w) {
  stage_slot(g, o.o0, lds, 0, w);
  stage_slot(g, o.o1, lds, 1, w);
  stage_slot(g, o.o2, lds, 2, w);
  stage_slot(g, o.o3, lds, 3, w);
}

__device__ __forceinline__ void k_iter(
    const unsigned short* Asc, const unsigned short* Bsc,
    unsigned short* Asn, unsigned short* Bsm,
    const unsigned short* gA, const Offs& oA,
    const unsigned short* gB, const Offs& oB,
    floatx4 (&acc)[8][4],
    int wm, int wn, int quad, int l16, int w, bool drain) {
  bf16x8 bfr[4][2], af[2][2];
  const int arow = wm * 128 + l16;
  const int brow = wn * 64 + l16;

#define READ_A2(m0)                                                       \
  _Pragma("unroll") for (int mi = 0; mi < 2; ++mi)                        \
      _Pragma("unroll") for (int kk = 0; kk < 2; ++kk) {                  \
    const int row = arow + ((m0) + mi) * 16;                              \
    const int ch = ((kk << 2) + quad) ^ (row & 7);                        \
    af[mi][kk] = *(const bf16x8*)(Asc + row * 64 + ch * 8);               \
  }
#define MMA2(m0)                                                          \
  __builtin_amdgcn_s_setprio(1);                                          \
  _Pragma("unroll") for (int mi = 0; mi < 2; ++mi)                        \
      _Pragma("unroll") for (int ni = 0; ni < 4; ++ni)                    \
          _Pragma("unroll") for (int kk = 0; kk < 2; ++kk)                \
    acc[(m0) + mi][ni] = __builtin_amdgcn_mfma_f32_16x16x32_bf16(         \
        af[mi][kk], bfr[ni][kk], acc[(m0) + mi][ni], 0, 0, 0);            \
  __builtin_amdgcn_s_setprio(0);

  // ---------------- phase 0: B hoist + A m0,m1 | stage A(u+1) ----------
#pragma unroll
  for (int ni = 0; ni < 4; ++ni)
#pragma unroll
    for (int kk = 0; kk < 2; ++kk) {
      const int row = brow + ni * 16;
      const int ch = ((kk << 2) + quad) ^ (row & 7);
      bfr[ni][kk] = *(const bf16x8*)(Bsc + row * 64 + ch * 8);
    }
  READ_A2(0)
  if (gA) stage4(gA, oA, Asn, w);
  __builtin_amdgcn_s_barrier();
  asm volatile("s_waitcnt lgkmcnt(0)" ::: "memory");
  __builtin_amdgcn_sched_barrier(0);
  MMA2(0)
  __builtin_amdgcn_s_barrier();
  // ---------------- phase 1: A m2,m3 | stage B(u+2) half0 --------------
  READ_A2(2)
  if (gB) { stage_slot(gB, oB.o0, Bsm, 0, w); stage_slot(gB, oB.o1, Bsm, 1, w); }
  __builtin_amdgcn_s_barrier();
  asm volatile("s_waitcnt lgkmcnt(0)" ::: "memory");
  __builtin_amdgcn_sched_barrier(0);
  MMA2(2)
  __builtin_amdgcn_s_barrier();
  // ---------------- phase 2: A m4,m5 | stage B(u+2) half1 --------------
  READ_A2(4)
  if (gB) { stage_slot(gB, oB.o2, Bsm, 2, w); stage_slot(gB, oB.o3, Bsm, 3, w); }
  __builtin_amdgcn_s_barrier();
  asm volatile("s_waitcnt lgkmcnt(0)" ::: "memory");
  __builtin_amdgcn_sched_barrier(0);
  MMA2(4)
  __builtin_amdgcn_s_barrier();
  // ---------------- phase 3: A m6,m7 | counted vmcnt -------------------
  READ_A2(6)
  if (drain) asm volatile("s_waitcnt vmcnt(0)" ::: "memory");
  else       asm volatile("s_waitcnt vmcnt(4)" ::: "memory");
  __builtin_amdgcn_s_barrier();
  asm volatile("s_waitcnt lgkmcnt(0)" ::: "memory");
  __builtin_amdgcn_sched_barrier(0);
  MMA2(6)
  __builtin_amdgcn_s_barrier();
#undef READ_A2
#undef MMA2
}

// XCD-grouped swizzle: give each XCD a contiguous band of M-tiles across all
// N-tiles so A-panels get L2 reuse. gm must be a multiple of 8 (C >= 2048).
__device__ __forceinline__ void swizzle(int b, int gm, int gn, int& m, int& n) {
  const int xcd = b & 7;
  const int idx = b >> 3;
  const int mloc = idx / gn;
  n = idx - mloc * gn;
  m = xcd * (gm >> 3) + mloc;
}

// - GEMM1 fused: Hl/Hh[t,f] = scale * gelu(x.W1^T + b1), scale = (1-p) or p --
__global__ __launch_bounds__(512, 2) void gemm1_fused_kernel(
    const unsigned short* __restrict__ Xb,   // [C, H] bf16
    const unsigned short* __restrict__ W1l,  // [1280, H] bf16 (rows>=1152 junk)
    const unsigned short* __restrict__ W1h,  // [4608, H] bf16
    const float* __restrict__ b1l,           // [FL] fp32
    const float* __restrict__ b1h,           // [FH] fp32
    const float* __restrict__ p1,            // [C]
    unsigned short* __restrict__ Hl,         // [C, FL] bf16
    unsigned short* __restrict__ Hh,         // [C, FH] bf16
    int gm) {
  __shared__ __align__(16) unsigned short As[2][256 * 64];
  __shared__ __align__(16) unsigned short Bs[2][256 * 64];
  const int tid = threadIdx.x;
  const int w = tid >> 6, lane = tid & 63;
  const int wm = w >> 2, wn = w & 3;
  const int quad = lane >> 4, l16 = lane & 15;

  int m, n;
  swizzle(blockIdx.x, gm, 23, m, n);       // 5 light (padded) + 18 heavy
  const int tm = m * 256;
  const bool heavy = n >= 5;
  const int tn = (heavy ? n - 5 : n) * 256;

  const unsigned short* Ab = Xb + (size_t)tm * H_DIM;
  const unsigned short* Bb = (heavy ? W1h : W1l) + (size_t)tn * H_DIM;
  const Offs off = make_offs(tid, H_DIM);  // lda = 1152 for both A and B

  floatx4 acc[8][4];
#pragma unroll
  for (int i = 0; i < 8; ++i)
#pragma unroll
    for (int j = 0; j < 4; ++j) acc[i][j] = (floatx4){0.f, 0.f, 0.f, 0.f};

  // prologue: tile0 A+B, tile1 B; keep tile1-B (last 4) in flight
  stage4(Ab, off, As[0], w);
  stage4(Bb, off, Bs[0], w);
  stage4(Bb + 64, off, Bs[1], w);
  asm volatile("s_waitcnt vmcnt(4)" ::: "memory");
  __builtin_amdgcn_s_barrier();
  __builtin_amdgcn_sched_barrier(0);

  const int NT = H_DIM / 64;  // 18 (even)
  for (int u = 0; u < NT; u += 2) {
    k_iter(As[0], Bs[0], As[1], Bs[0],
           (u + 1 < NT) ? Ab + (u + 1) * 64 : nullptr, off,
           (u + 2 < NT) ? Bb + (u + 2) * 64 : nullptr, off,
           acc, wm, wn, quad, l16, w, u + 2 >= NT);
    k_iter(As[1], Bs[1], As[0], Bs[1],
           (u + 2 < NT) ? Ab + (u + 2) * 64 : nullptr, off,
           (u + 3 < NT) ? Bb + (u + 3) * 64 : nullptr, off,
           acc, wm, wn, quad, l16, w, u + 3 >= NT);
  }

  const int colb = tn + wn * 64 + l16;
  const int trow = tm + wm * 128 + quad * 4;
  if (heavy) {
    float bias[4];
#pragma unroll
    for (int ni = 0; ni < 4; ++ni) bias[ni] = b1h[colb + ni * 16];
#pragma unroll
    for (int mi = 0; mi < 8; ++mi)
#pragma unroll
      for (int r = 0; r < 4; ++r) {
        const int gtok = trow + mi * 16 + r;
        const float pv = p1[gtok];
#pragma unroll
        for (int ni = 0; ni < 4; ++ni) {
          const float v = acc[mi][ni][r] + bias[ni];
          const float g = 0.5f * v * (1.f + erff(v * 0.70710678118f));
          Hh[(size_t)gtok * FH_DIM + colb + ni * 16] = f2bf(g * pv);
        }
      }
  } else {
    float bias[4];
#pragma unroll
    for (int ni = 0; ni < 4; ++ni) {
      const int col = colb + ni * 16;
      bias[ni] = (col < FL_DIM) ? b1l[col] : 0.f;
    }
#pragma unroll
    for (int mi = 0; mi < 8; ++mi)
#pragma unroll
      for (int r = 0; r < 4; ++r) {
        const int gtok = trow + mi * 16 + r;
        const float pv = p1[gtok];
        const float sc = 1.f - pv;
#pragma unroll
        for (int ni = 0; ni < 4; ++ni) {
          const int col = colb + ni * 16;
          if (col < FL_DIM) {
            const float v = acc[mi][ni][r] + bias[ni];
            const float g = 0.5f * v * (1.f + erff(v * 0.70710678118f));
            Hl[(size_t)gtok * FL_DIM + col] = f2bf(g * sc);
          }
        }
      }
  }
}

// -- GEMM2: out[t,h] = Hl.W2l^T + Hh.W2h^T + (1-p1)b2l + p1*b2h (K = 5760) ---
__global__ __launch_bounds__(512, 2) void gemm2_kernel(
    const unsigned short* __restrict__ Hl,   // [C, FL] bf16
    const unsigned short* __restrict__ Hh,   // [C, FH] bf16
    const unsigned short* __restrict__ W2l,  // [1280, FL] bf16 (rows>=1152 junk)
    const unsigned short* __restrict__ W2h,  // [1280, FH] bf16
    const float* __restrict__ b2l,           // [H] fp32
    const float* __restrict__ b2h,           // [H] fp32
    const float* __restrict__ p1,            // [C]
    float* __restrict__ Out,                 // [C, H] fp32
    int gm) {
  __shared__ __align__(16) unsigned short As[2][256 * 64];
  __shared__ __align__(16) unsigned short Bs[2][256 * 64];
  const int tid = threadIdx.x;
  const int w = tid >> 6, lane = tid & 63;
  const int wm = w >> 2, wn = w & 3;
  const int quad = lane >> 4, l16 = lane & 15;

  int m, n;
  swizzle(blockIdx.x, gm, 5, m, n);        // N padded 1152 -> 1280
  const int tm = m * 256;
  const int tn = n * 256;

  const unsigned short* AL = Hl + (size_t)tm * FL_DIM;
  const unsigned short* AH = Hh + (size_t)tm * FH_DIM;
  const unsigned short* BL = W2l + (size_t)tn * FL_DIM;
  const unsigned short* BH = W2h + (size_t)tn * FH_DIM;
  const Offs offL = make_offs(tid, FL_DIM);
  const Offs offH = make_offs(tid, FH_DIM);

  const int KT1 = FL_DIM / 64;             // 18
  const int NT = KT1 + FH_DIM / 64;        // 90 (even)

  auto gAt = [&](int t) -> const unsigned short* {
    if (t >= NT) return nullptr;
    return (t < KT1) ? AL + t * 64 : AH + (size_t)(t - KT1) * 64;
  };
  auto gBt = [&](int t) -> const unsigned short* {
    if (t >= NT) return nullptr;
    return (t < KT1) ? BL + t * 64 : BH + (size_t)(t - KT1) * 64;
  };

  floatx4 acc[8][4];
#pragma unroll
  for (int i = 0; i < 8; ++i)
#pragma unroll
    for (int j = 0; j < 4; ++j) acc[i][j] = (floatx4){0.f, 0.f, 0.f, 0.f};

  stage4(gAt(0), offL, As[0], w);
  stage4(gBt(0), offL, Bs[0], w);
  stage4(gBt(1), offL, Bs[1], w);
  asm volatile("s_waitcnt vmcnt(4)" ::: "memory");
  __builtin_amdgcn_s_barrier();
  __builtin_amdgcn_sched_barrier(0);

  for (int u = 0; u < NT; u += 2) {
    {
      const int t1 = u + 1, t2 = u + 2;
      k_iter(As[0], Bs[0], As[1], Bs[0],
             gAt(t1), (t1 < KT1) ? offL : offH,
             gBt(t2), (t2 < KT1) ? offL : offH,
             acc, wm, wn, quad, l16, w, t2 >= NT);
    }
    {
      const int t1 = u + 2, t2 = u + 3;
      k_iter(As[1], Bs[1], As[0], Bs[1],
             gAt(t1), (t1 < KT1) ? offL : offH,
             gBt(t2), (t2 < KT1) ? offL : offH,
             acc, wm, wn, quad, l16, w, t2 >= NT);
    }
  }

  const int colb = tn + wn * 64 + l16;
  const int trow = tm + wm * 128 + quad * 4;
  float bl[4], bh[4];
#pragma unroll
  for (int ni = 0; ni < 4; ++ni) {
    const int col = colb + ni * 16;
    const bool ok = col < H_DIM;
    bl[ni] = ok ? b2l[col] : 0.f;
    bh[ni] = ok ? b2h[col] : 0.f;
  }
#pragma unroll
  for (int mi = 0; mi < 8; ++mi)
#pragma unroll
    for (int r = 0; r < 4; ++r) {
      const int gtok = trow + mi * 16 + r;
      const float pv = p1[gtok];
#pragma unroll
      for (int ni = 0; ni < 4; ++ni) {
        const int col = colb + ni * 16;
        if (col < H_DIM)
          Out[(size_t)gtok * H_DIM + col] = acc[mi][ni][r] + bl[ni] + pv * (bh[ni] - bl[ni]);
      }
    }
}

extern "C" void kernel_launch(void* const* d_in, const int* in_sizes, int n_in,
                              void* d_out, int out_size, void* d_ws, size_t ws_size,
                              hipStream_t stream) {
  const float* x   = (const float*)d_in[0];
  const float* rw  = (const float*)d_in[1];
  const float* rb  = (const float*)d_in[2];
  const float* lw1 = (const float*)d_in[3];
  const float* lb1 = (const float*)d_in[4];
  const float* lw2 = (const float*)d_in[5];
  const float* lb2 = (const float*)d_in[6];
  const float* hw1 = (const float*)d_in[7];
  const float* hb1 = (const float*)d_in[8];
  const float* hw2 = (const float*)d_in[9];
  const float* hb2 = (const float*)d_in[10];
  float* out = (float*)d_out;

  // ---- workspace layout (padded weight buffers for 256-wide N-tiles) ----
  const size_t N_LW1 = (size_t)FL_PAD * H_DIM;   // [1280,1152]
  const size_t N_HW1 = (size_t)FH_DIM * H_DIM;   // [4608,1152]
  const size_t N_LW2 = (size_t)H_PAD * FL_DIM;   // [1280,1152]
  const size_t N_HW2 = (size_t)H_PAD * FH_DIM;   // [1280,4608]
  char* p = (char*)d_ws;
  float* p1 = (float*)p;                     p += (size_t)NTOK * 4;
  unsigned short* lw1b = (unsigned short*)p; p += N_LW1 * 2;
  unsigned short* hw1b = (unsigned short*)p; p += N_HW1 * 2;
  unsigned short* lw2b = (unsigned short*)p; p += N_LW2 * 2;
  unsigned short* hw2b = (unsigned short*)p; p += N_HW2 * 2;
  unsigned short* xb   = (unsigned short*)p; p += (size_t)NTOK * H_DIM * 2;
  const size_t fixed = (size_t)(p - (char*)d_ws);

  // tokens per chunk: hl (C*FL*2) + hh (C*FH*2) = C*11520 bytes; C % 256 == 0
  int C = NTOK;
  while (C > 2048 && fixed + (size_t)C * 11520 > ws_size) C >>= 1;
  unsigned short* hl = (unsigned short*)p;
  unsigned short* hh = hl + (size_t)C * FL_DIM;

  // ---- weight conversions (fp32 -> bf16; real rows only, pad rows junk) ----
  cvt_kernel<<<(int)((size_t)FL_DIM * H_DIM / 1024), 256, 0, stream>>>(
      lw1, lw1b, (int)((size_t)FL_DIM * H_DIM / 4));
  cvt_kernel<<<(int)((size_t)FH_DIM * H_DIM / 1024), 256, 0, stream>>>(
      hw1, hw1b, (int)((size_t)FH_DIM * H_DIM / 4));
  cvt_kernel<<<(int)((size_t)H_DIM * FL_DIM / 1024), 256, 0, stream>>>(
      lw2, lw2b, (int)((size_t)H_DIM * FL_DIM / 4));
  cvt_kernel<<<(int)((size_t)H_DIM * FH_DIM / 1024), 256, 0, stream>>>(
      hw2, hw2b, (int)((size_t)H_DIM * FH_DIM / 4));

  router_cvt_kernel<<<NTOK / 4, 256, 0, stream>>>(x, rw, rb, p1, xb);

  for (int c0 = 0; c0 < NTOK; c0 += C) {
    const int gm = C / 256;
    gemm1_fused_kernel<<<gm * 23, 512, 0, stream>>>(
        xb + (size_t)c0 * H_DIM, lw1b, hw1b, lb1, hb1, p1 + c0, hl, hh, gm);
    gemm2_kernel<<<gm * 5, 512, 0, stream>>>(
        hl, hh, lw2b, hw2b, lb2, hb2, p1 + c0, out + (size_t)c0 * H_DIM, gm);
  }
}